// Round 3
// baseline (10450.550 us; speedup 1.0000x reference)
//
#include <hip/hip_runtime.h>
#include <hip/hip_bf16.h>
#include <math.h>

// Problem constants (fixed by setup_inputs): B=64, L=512, D_IN=256, H=256, A=128, DEPTH=4
#define BB 64
#define LL 512
#define HH 256
#define H3 768
#define AA 128
#define NDEPTH 4
#define NROWS (LL*BB)   // 32768

// exchange region (carved from the dead Xc buffer each depth):
//   float exch[64][2][3][256]  (1,572,864 B) then int flags[64][3*16] (12,288 B)
#define EXCH_FLOATS (64 * 2 * 3 * 256)
#define FLAG_STRIDE 48          // ints per chain (3 slices x 16-int padding)
#define FLAG_BYTES  (64 * FLAG_STRIDE * 4)

// ---------------------------------------------------------------------------
// Mask conversion: detect byte-bool vs int32/float32 layout on device.
// mask[0][1] is always true (lengths >= 256 > 1): byte layout -> raw[1]==1.
__global__ void maskcvt_kernel(const unsigned char* __restrict__ raw,
                               int* __restrict__ m)
{
    int i = blockIdx.x * blockDim.x + threadIdx.x;   // 32768 threads
    bool bytemode = (raw[1] == 1);
    int v;
    if (bytemode) v = raw[i] ? 1 : 0;
    else          v = (((const int*)raw)[i] != 0) ? 1 : 0;
    m[i] = v;
}

// ---------------------------------------------------------------------------
// Tiled fp32 GEMM: C[M,N] = A[M,256] @ B[256,N]  (K fixed at 256)
// MODE 0: A[row,k] = A[row*256+k]
// MODE 1: A[row,k] = A[(row&63)*131072 + (row>>6)*256 + k]   (x gather)
// MODE 2: A[row,k] = row<64 ? 0 : A[(row-64)*256+k]          (Hprev shift)
// EPI 0: store acc; EPI 1: + bias[col]; EPI 2: tanh(acc + aux[row*N+col])
template<int MODE, int EPI>
__global__ __launch_bounds__(256) void gemm_kernel(
    const float* __restrict__ A, const float* __restrict__ Bm,
    const float* __restrict__ bias, const float* __restrict__ aux,
    float* __restrict__ C, int M, int N)
{
    __shared__ float As[16][136];
    __shared__ float Bs[16][136];
    const int tid = threadIdx.x;
    const int tx = tid & 15, ty = tid >> 4;
    const int row0 = blockIdx.y * 128, col0 = blockIdx.x * 128;

    float acc[8][8];
#pragma unroll
    for (int i = 0; i < 8; ++i)
#pragma unroll
        for (int j = 0; j < 8; ++j) acc[i][j] = 0.f;

    for (int kk = 0; kk < 256; kk += 16) {
#pragma unroll
        for (int i = 0; i < 2; ++i) {
            int aid = i * 256 + tid;
            int r   = aid >> 2;
            int k4  = (aid & 3) << 2;
            int rr  = row0 + r;
            float4 v;
            if (MODE == 0) {
                v = *(const float4*)(A + rr * 256 + kk + k4);
            } else if (MODE == 1) {
                v = *(const float4*)(A + (rr & 63) * 131072 + (rr >> 6) * 256 + kk + k4);
            } else {
                if (rr < 64) v = make_float4(0.f, 0.f, 0.f, 0.f);
                else         v = *(const float4*)(A + (rr - 64) * 256 + kk + k4);
            }
            As[k4 + 0][r] = v.x; As[k4 + 1][r] = v.y;
            As[k4 + 2][r] = v.z; As[k4 + 3][r] = v.w;

            int bid = i * 256 + tid;
            int bk  = bid >> 5;
            int c4  = (bid & 31) << 2;
            float4 w = *(const float4*)(Bm + (kk + bk) * N + col0 + c4);
            *(float4*)&Bs[bk][c4] = w;
        }
        __syncthreads();
#pragma unroll
        for (int k = 0; k < 16; ++k) {
            float a[8], bb2[8];
            *(float4*)&a[0]   = *(const float4*)&As[k][ty * 8];
            *(float4*)&a[4]   = *(const float4*)&As[k][ty * 8 + 4];
            *(float4*)&bb2[0] = *(const float4*)&Bs[k][tx * 8];
            *(float4*)&bb2[4] = *(const float4*)&Bs[k][tx * 8 + 4];
#pragma unroll
            for (int i = 0; i < 8; ++i)
#pragma unroll
                for (int j = 0; j < 8; ++j)
                    acc[i][j] += a[i] * bb2[j];
        }
        __syncthreads();
    }

#pragma unroll
    for (int i = 0; i < 8; ++i) {
        int row  = row0 + ty * 8 + i;
        int colb = col0 + tx * 8;
        float vout[8];
#pragma unroll
        for (int j = 0; j < 8; ++j) {
            float v = acc[i][j];
            if (EPI == 1) v += bias[colb + j];
            if (EPI == 2) v = tanhf(v + aux[row * N + colb + j]);
            vout[j] = v;
        }
        *(float4*)&C[row * N + colb]     = *(float4*)&vout[0];
        *(float4*)&C[row * N + colb + 4] = *(float4*)&vout[4];
    }
}

// ---------------------------------------------------------------------------
// Row LayerNorm over 768 cols, in place, fused with gamma/beta and gate bias.
__global__ __launch_bounds__(256) void lnrows_kernel(
    float* __restrict__ XP, const float* __restrict__ g0,
    const float* __restrict__ b0, const float* __restrict__ gb)
{
    const int row = blockIdx.x;
    const int tid = threadIdx.x;
    float* p = XP + (long)row * H3;
    float v0 = p[tid], v1 = p[tid + 256], v2 = p[tid + 512];
    float s = v0 + v1 + v2;
    float q = v0 * v0 + v1 * v1 + v2 * v2;
#pragma unroll
    for (int off = 32; off >= 1; off >>= 1) {
        s += __shfl_xor(s, off);
        q += __shfl_xor(q, off);
    }
    __shared__ float rs4[4], rq4[4];
    if ((tid & 63) == 0) { rs4[tid >> 6] = s; rq4[tid >> 6] = q; }
    __syncthreads();
    float S = rs4[0] + rs4[1] + rs4[2] + rs4[3];
    float Q = rq4[0] + rq4[1] + rq4[2] + rq4[3];
    float mu  = S * (1.f / 768.f);
    float var = Q * (1.f / 768.f) - mu * mu;
    float r   = rsqrtf(var + 1e-5f);
    p[tid]       = g0[tid]       * (v0 - mu) * r + b0[tid]       + gb[tid];
    p[tid + 256] = g0[tid + 256] * (v1 - mu) * r + b0[tid + 256] + gb[tid + 256];
    p[tid + 512] = g0[tid + 512] * (v2 - mu) * r + b0[tid + 512] + gb[tid + 512];
}

// ---------------------------------------------------------------------------
// Sequential GRU scan, 3 workgroups per chain (grid = 192, one wg per CU).
// wg (s = blockIdx.x>>6, b = blockIdx.x&63) owns U columns [s*256,(s+1)*256):
// thread (g=tid>>7, t=tid&127) holds 64 U values in registers.
// amdgpu_waves_per_eu(4,4) pins the allocator to the 128-VGPR tier (16 waves/CU
// = exactly 1 wg/CU) so the u-slice STAYS register-resident (round-2 post-mortem:
// VGPR_Count=64 => slice demoted, U re-streamed from L2 every step, 4.1us/step).
// Per active step: slice GEMV -> publish 256 pre-LN floats via per-wave
// release flags (device scope, parity double-buffered) -> idle waves spin on
// peers -> all wgs redundantly compute LN+gates+h. Masked steps: row copy only.
__global__ __attribute__((amdgpu_flat_work_group_size(1024, 1024)))
           __attribute__((amdgpu_waves_per_eu(4, 4)))
void scan3_kernel(
    const float* __restrict__ XP,   // (L*B, 768), row=(l*64+b), bias+LN folded
    const float* __restrict__ U,    // (256, 768)
    const float* __restrict__ g1, const float* __restrict__ b1,
    const int* __restrict__ mask,   // [b*512+l]
    float* __restrict__ Y,          // (L*B, 256)
    float* __restrict__ exch,       // [64][2][3][256]
    int* __restrict__ flags)        // [64][FLAG_STRIDE], memset 0 pre-launch
{
    const int wg  = blockIdx.x;
    const int b   = wg & 63;
    const int s   = wg >> 6;               // slice 0..2
    const int tid = threadIdx.x;
    const int g   = tid >> 7;
    const int t   = tid & 127;
    const int kb  = g << 5;
    const int p1  = (s + 1 >= 3) ? s - 2 : s + 1;
    const int p2  = (s + 2 >= 3) ? s - 1 : s + 2;

    __shared__ float h_cur[256];
    __shared__ float part[8][256];
    __shared__ float xp_lds[768];
    __shared__ float g1s[768], b1s[768];
    __shared__ int   mk[512];
    __shared__ float reds[4], redq[4];

    // U slice -> registers (coalesced across t for each k)
    float u0[32], u1[32];
    {
        const float* Ub = U + s * 256 + t;
#pragma unroll
        for (int k = 0; k < 32; ++k) {
            u0[k] = Ub[(kb + k) * H3];
            u1[k] = Ub[(kb + k) * H3 + 128];
        }
    }
    if (tid < 256) h_cur[tid] = 0.f;
    if (tid < 768) { g1s[tid] = g1[tid]; b1s[tid] = b1[tid]; }
    if (tid < 512) mk[tid] = mask[b * LL + tid];
    __syncthreads();

    float* exb = exch + b * (2 * 3 * 256);
    int*   flb = flags + b * FLAG_STRIDE;
    int seq = 0;

    for (int l = 0; l < LL; ++l) {
        if (!mk[l]) {
            // masked step: h unchanged, Y row = h (slice 0 writes)
            if (s == 0 && tid < 64) {
                float4 hv = *(const float4*)&h_cur[tid * 4];
                *(float4*)&Y[((long)l * BB + b) * HH + tid * 4] = hv;
            }
            continue;
        }
        seq++;
        const int par = seq & 1;

        // prefetch xp row (in flight during GEMV + exchange)
        float4 xr4;
        if (tid < 192) xr4 = *(const float4*)(XP + ((long)l * BB + b) * H3 + tid * 4);

        // slice GEMV: pre[c*128+t] = sum_k u[c][k] * h[kb+k], partial per g
        float a0 = 0.f, a1 = 0.f;
#pragma unroll
        for (int i = 0; i < 8; ++i) {
            float4 hv = *(const float4*)&h_cur[kb + i * 4];
            a0 += u0[i*4+0]*hv.x + u0[i*4+1]*hv.y + u0[i*4+2]*hv.z + u0[i*4+3]*hv.w;
            a1 += u1[i*4+0]*hv.x + u1[i*4+1]*hv.y + u1[i*4+2]*hv.z + u1[i*4+3]*hv.w;
        }
        part[g][t]       = a0;
        part[g][128 + t] = a1;
        __syncthreads();                               // B1: part complete

        // waves 0-3 (tid<256): reduce own column, publish, per-wave release
        // flag (release waits only this wave's outstanding stores).
        float pre = 0.f;
        if (tid < 256) {
            pre = part[0][tid];
#pragma unroll
            for (int gg = 1; gg < 8; ++gg) pre += part[gg][tid];
            __hip_atomic_store(&exb[(par * 3 + s) * 256 + tid], pre,
                               __ATOMIC_RELAXED, __HIP_MEMORY_SCOPE_AGENT);
            if ((tid & 63) == 0)
                __hip_atomic_store(&flb[s * 16 + (tid >> 6)], seq,
                                   __ATOMIC_RELEASE, __HIP_MEMORY_SCOPE_AGENT);
        }
        if (tid < 192) *(float4*)&xp_lds[tid * 4] = xr4;
        // otherwise-idle waves poll the 8 peer wave-flags (2 peers x 4 waves)
        if (tid >= 256 && tid < 264) {
            int ps = ((tid - 256) >> 2) ? p2 : p1;
            int w  = (tid - 256) & 3;
            while (__hip_atomic_load(&flb[ps * 16 + w],
                                     __ATOMIC_ACQUIRE, __HIP_MEMORY_SCOPE_AGENT) < seq) {}
        }
        __syncthreads();                               // B3: peers published

        // read peer slices + LN stats
        float v0 = 0.f, v1 = 0.f, v2 = 0.f;
        if (tid < 256) {
            float w1 = __hip_atomic_load(&exb[(par * 3 + p1) * 256 + tid],
                                         __ATOMIC_RELAXED, __HIP_MEMORY_SCOPE_AGENT);
            float w2 = __hip_atomic_load(&exb[(par * 3 + p2) * 256 + tid],
                                         __ATOMIC_RELAXED, __HIP_MEMORY_SCOPE_AGENT);
            v0 = (s == 0) ? pre : ((p1 == 0) ? w1 : w2);
            v1 = (s == 1) ? pre : ((p1 == 1) ? w1 : w2);
            v2 = (s == 2) ? pre : ((p1 == 2) ? w1 : w2);
            float st = v0 + v1 + v2;
            float qt = v0 * v0 + v1 * v1 + v2 * v2;
#pragma unroll
            for (int off = 32; off >= 1; off >>= 1) {
                st += __shfl_xor(st, off);
                qt += __shfl_xor(qt, off);
            }
            if ((tid & 63) == 0) { reds[tid >> 6] = st; redq[tid >> 6] = qt; }
        }
        __syncthreads();                               // B4: stats partials

        if (tid < 256) {
            float S = reds[0] + reds[1] + reds[2] + reds[3];
            float Q = redq[0] + redq[1] + redq[2] + redq[3];
            float mu = S * (1.f / 768.f);
            float rs = rsqrtf(Q * (1.f / 768.f) - mu * mu + 1e-5f);
            float hp_r = g1s[tid]       * (v0 - mu) * rs + b1s[tid];
            float hp_z = g1s[256 + tid] * (v1 - mu) * rs + b1s[256 + tid];
            float hp_h = g1s[512 + tid] * (v2 - mu) * rs + b1s[512 + tid];
            float xr = xp_lds[tid], xz = xp_lds[256 + tid], xh = xp_lds[512 + tid];
            float r  = 1.f / (1.f + expf(-(xr + hp_r)));
            float z  = 1.f / (1.f + expf(-(xz + hp_z)));
            float hh = tanhf(xh + r * hp_h);
            float o  = z * h_cur[tid] + (1.f - z) * hh;   // active step: mt=1
            h_cur[tid] = o;
            if (s == 0) Y[((long)l * BB + b) * HH + tid] = o;
        }
        __syncthreads();                               // B5: h_cur ready
    }
}

// ---------------------------------------------------------------------------
// Action head: per row (l,b): logits = T[row,:] @ Wa2 + ba2, softmax, decision.
__global__ __launch_bounds__(256) void act_kernel(
    const float* __restrict__ T, const float* __restrict__ Wa2,
    const float* __restrict__ ba2, const int* __restrict__ mask_in,
    int* __restrict__ mask_out, float* __restrict__ act_out,
    float* __restrict__ pol_out, int d)
{
    int row  = blockIdx.x * 4 + (threadIdx.x >> 6);
    int lane = threadIdx.x & 63;
    const float* Tr = T + (long)row * AA;
    float t0 = Tr[lane], t1 = Tr[lane + 64];
    float l0 = t0 * Wa2[lane * 2]       + t1 * Wa2[(lane + 64) * 2];
    float l1 = t0 * Wa2[lane * 2 + 1]   + t1 * Wa2[(lane + 64) * 2 + 1];
#pragma unroll
    for (int off = 32; off >= 1; off >>= 1) {
        l0 += __shfl_xor(l0, off);
        l1 += __shfl_xor(l1, off);
    }
    if (lane == 0) {
        int l = row >> 6, bb = row & 63;
        l0 += ba2[0]; l1 += ba2[1];
        float m  = fmaxf(l0, l1);
        float e0 = expf(l0 - m), e1 = expf(l1 - m);
        float inv = 1.f / (e0 + e1);
        float p0 = e0 * inv, p1 = e1 * inv;
        int mt = mask_in[bb * LL + l];
        int a  = (p1 > p0) && mt;
        act_out[bb * (NDEPTH * LL) + d * LL + l] = a ? 1.f : 0.f;
        pol_out[bb * (NDEPTH * LL * 2) + d * (LL * 2) + l * 2 + 0] = p0;
        pol_out[bb * (NDEPTH * LL * 2) + d * (LL * 2) + l * 2 + 1] = p1;
        mask_out[bb * LL + l] = a;
    }
}

// ---------------------------------------------------------------------------
__global__ void final_copy_kernel(const float* __restrict__ X, float* __restrict__ out)
{
    int i = blockIdx.x * blockDim.x + threadIdx.x;   // 16384
    int bb = i >> 8, j = i & 255;
    out[i] = X[((long)(LL - 1) * BB + bb) * HH + j];
}

// ---------------------------------------------------------------------------
extern "C" void kernel_launch(void* const* d_in, const int* in_sizes, int n_in,
                              void* d_out, int out_size, void* d_ws, size_t ws_size,
                              hipStream_t stream)
{
    const float* x      = (const float*)d_in[0];
    const void*  mraw   = d_in[1];
    const float* W_emb  = (const float*)d_in[2];
    const float* b_emb  = (const float*)d_in[3];
    const float* W      = (const float*)d_in[4];
    const float* U      = (const float*)d_in[5];
    const float* bias3  = (const float*)d_in[6];
    const float* Wa1    = (const float*)d_in[7];
    const float* Ua1    = (const float*)d_in[8];
    const float* ba1    = (const float*)d_in[9];
    const float* Wa2    = (const float*)d_in[10];
    const float* ba2    = (const float*)d_in[11];
    const float* gammas = (const float*)d_in[12];
    const float* betas  = (const float*)d_in[13];

    float* out = (float*)d_out;
    char*  ws  = (char*)d_ws;

    // workspace layout (bytes) — unchanged (<= 184.9 MB)
    float* XP = (float*)(ws);                                   // 100663296
    float* X  = (float*)(ws + 100663296UL);                     // 33554432
    float* Y  = (float*)(ws + 134217728UL);                     // 33554432
    float* XA = (float*)(ws + 167772160UL);                     // 16777216
    float* T  = XP;  // alias: XP dead between scan and next-depth GEMM
    int*   m0 = (int*)(ws + 184549376UL);                       // 131072
    int*   m1 = (int*)(ws + 184680448UL);                       // 131072

    float* act_out = out + BB * HH;                             // 16384
    float* pol_out = act_out + BB * NDEPTH * LL;                // +131072

    maskcvt_kernel<<<dim3(NROWS / 256), dim3(256), 0, stream>>>(
        (const unsigned char*)mraw, m0);

    // embedding: X = x @ W_emb + b_emb, time-major rows (l*64+b)
    gemm_kernel<1, 1><<<dim3(2, 256), dim3(256), 0, stream>>>(
        x, W_emb, b_emb, nullptr, X, NROWS, HH);

    float* Xc = X; float* Yc = Y;
    int* mc = m0; int* mn = m1;

    for (int d = 0; d < NDEPTH; ++d) {
        gemm_kernel<0, 0><<<dim3(6, 256), dim3(256), 0, stream>>>(
            Xc, W, nullptr, nullptr, XP, NROWS, H3);
        lnrows_kernel<<<dim3(NROWS), dim3(256), 0, stream>>>(
            XP, gammas, betas, bias3);
        gemm_kernel<0, 1><<<dim3(1, 256), dim3(256), 0, stream>>>(
            Xc, Wa1, ba1, nullptr, XA, NROWS, AA);

        // exchange + flags live in the now-dead Xc buffer (disjoint from Yc)
        float* exch_d  = Xc;
        int*   flags_d = (int*)(Xc + EXCH_FLOATS);
        hipMemsetAsync(flags_d, 0, FLAG_BYTES, stream);

        scan3_kernel<<<dim3(192), dim3(1024), 0, stream>>>(
            XP, U, gammas + H3, betas + H3, mc, Yc, exch_d, flags_d);

        gemm_kernel<2, 2><<<dim3(1, 256), dim3(256), 0, stream>>>(
            Yc, Ua1, nullptr, XA, T, NROWS, AA);
        act_kernel<<<dim3(NROWS / 4), dim3(256), 0, stream>>>(
            T, Wa2, ba2, mc, mn, act_out, pol_out, d);
        { float* tmp = Xc; Xc = Yc; Yc = tmp; }
        { int* tmp = mc; mc = mn; mn = tmp; }
    }

    final_copy_kernel<<<dim3(BB), dim3(256), 0, stream>>>(Xc, out);
}

// Round 4
// 5484.998 us; speedup vs baseline: 1.9053x; 1.9053x over previous
//
#include <hip/hip_runtime.h>
#include <hip/hip_bf16.h>
#include <math.h>

// Problem constants (fixed by setup_inputs): B=64, L=512, D_IN=256, H=256, A=128, DEPTH=4
#define BB 64
#define LL 512
#define HH 256
#define H3 768
#define AA 128
#define NDEPTH 4
#define NROWS (LL*BB)   // 32768

// exchange region (carved from the dead Xc buffer each depth):
//   float exch[64][2][3][256]  (1,572,864 B) then int flags[64][3*16] (12,288 B)
#define EXCH_FLOATS (64 * 2 * 3 * 256)
#define FLAG_STRIDE 48          // ints per chain (3 slices x 16-int padding)
#define FLAG_BYTES  (64 * FLAG_STRIDE * 4)

// first-class vector type: lives in VGPRs, never an alloca (round-2/3
// post-mortem: float u[32] arrays were kept in SCRATCH by promote-alloca's
// occupancy heuristic -> 107-114 GB/dispatch of spill traffic in the scan)
typedef float vf32x32 __attribute__((ext_vector_type(32)));

// ---------------------------------------------------------------------------
// Mask conversion: detect byte-bool vs int32/float32 layout on device.
// mask[0][1] is always true (lengths >= 256 > 1): byte layout -> raw[1]==1.
__global__ void maskcvt_kernel(const unsigned char* __restrict__ raw,
                               int* __restrict__ m)
{
    int i = blockIdx.x * blockDim.x + threadIdx.x;   // 32768 threads
    bool bytemode = (raw[1] == 1);
    int v;
    if (bytemode) v = raw[i] ? 1 : 0;
    else          v = (((const int*)raw)[i] != 0) ? 1 : 0;
    m[i] = v;
}

// ---------------------------------------------------------------------------
// Tiled fp32 GEMM: C[M,N] = A[M,256] @ B[256,N]  (K fixed at 256)
// MODE 0: A[row,k] = A[row*256+k]
// MODE 1: A[row,k] = A[(row&63)*131072 + (row>>6)*256 + k]   (x gather)
// MODE 2: A[row,k] = row<64 ? 0 : A[(row-64)*256+k]          (Hprev shift)
// EPI 0: store acc; EPI 1: + bias[col]; EPI 2: tanh(acc + aux[row*N+col])
template<int MODE, int EPI>
__global__ __launch_bounds__(256) void gemm_kernel(
    const float* __restrict__ A, const float* __restrict__ Bm,
    const float* __restrict__ bias, const float* __restrict__ aux,
    float* __restrict__ C, int M, int N)
{
    __shared__ float As[16][136];
    __shared__ float Bs[16][136];
    const int tid = threadIdx.x;
    const int tx = tid & 15, ty = tid >> 4;
    const int row0 = blockIdx.y * 128, col0 = blockIdx.x * 128;

    float acc[8][8];
#pragma unroll
    for (int i = 0; i < 8; ++i)
#pragma unroll
        for (int j = 0; j < 8; ++j) acc[i][j] = 0.f;

    for (int kk = 0; kk < 256; kk += 16) {
#pragma unroll
        for (int i = 0; i < 2; ++i) {
            int aid = i * 256 + tid;
            int r   = aid >> 2;
            int k4  = (aid & 3) << 2;
            int rr  = row0 + r;
            float4 v;
            if (MODE == 0) {
                v = *(const float4*)(A + rr * 256 + kk + k4);
            } else if (MODE == 1) {
                v = *(const float4*)(A + (rr & 63) * 131072 + (rr >> 6) * 256 + kk + k4);
            } else {
                if (rr < 64) v = make_float4(0.f, 0.f, 0.f, 0.f);
                else         v = *(const float4*)(A + (rr - 64) * 256 + kk + k4);
            }
            As[k4 + 0][r] = v.x; As[k4 + 1][r] = v.y;
            As[k4 + 2][r] = v.z; As[k4 + 3][r] = v.w;

            int bid = i * 256 + tid;
            int bk  = bid >> 5;
            int c4  = (bid & 31) << 2;
            float4 w = *(const float4*)(Bm + (kk + bk) * N + col0 + c4);
            *(float4*)&Bs[bk][c4] = w;
        }
        __syncthreads();
#pragma unroll
        for (int k = 0; k < 16; ++k) {
            float a[8], bb2[8];
            *(float4*)&a[0]   = *(const float4*)&As[k][ty * 8];
            *(float4*)&a[4]   = *(const float4*)&As[k][ty * 8 + 4];
            *(float4*)&bb2[0] = *(const float4*)&Bs[k][tx * 8];
            *(float4*)&bb2[4] = *(const float4*)&Bs[k][tx * 8 + 4];
#pragma unroll
            for (int i = 0; i < 8; ++i)
#pragma unroll
                for (int j = 0; j < 8; ++j)
                    acc[i][j] += a[i] * bb2[j];
        }
        __syncthreads();
    }

#pragma unroll
    for (int i = 0; i < 8; ++i) {
        int row  = row0 + ty * 8 + i;
        int colb = col0 + tx * 8;
        float vout[8];
#pragma unroll
        for (int j = 0; j < 8; ++j) {
            float v = acc[i][j];
            if (EPI == 1) v += bias[colb + j];
            if (EPI == 2) v = tanhf(v + aux[row * N + colb + j]);
            vout[j] = v;
        }
        *(float4*)&C[row * N + colb]     = *(float4*)&vout[0];
        *(float4*)&C[row * N + colb + 4] = *(float4*)&vout[4];
    }
}

// ---------------------------------------------------------------------------
// Row LayerNorm over 768 cols, in place, fused with gamma/beta and gate bias.
__global__ __launch_bounds__(256) void lnrows_kernel(
    float* __restrict__ XP, const float* __restrict__ g0,
    const float* __restrict__ b0, const float* __restrict__ gb)
{
    const int row = blockIdx.x;
    const int tid = threadIdx.x;
    float* p = XP + (long)row * H3;
    float v0 = p[tid], v1 = p[tid + 256], v2 = p[tid + 512];
    float s = v0 + v1 + v2;
    float q = v0 * v0 + v1 * v1 + v2 * v2;
#pragma unroll
    for (int off = 32; off >= 1; off >>= 1) {
        s += __shfl_xor(s, off);
        q += __shfl_xor(q, off);
    }
    __shared__ float rs4[4], rq4[4];
    if ((tid & 63) == 0) { rs4[tid >> 6] = s; rq4[tid >> 6] = q; }
    __syncthreads();
    float S = rs4[0] + rs4[1] + rs4[2] + rs4[3];
    float Q = rq4[0] + rq4[1] + rq4[2] + rq4[3];
    float mu  = S * (1.f / 768.f);
    float var = Q * (1.f / 768.f) - mu * mu;
    float r   = rsqrtf(var + 1e-5f);
    p[tid]       = g0[tid]       * (v0 - mu) * r + b0[tid]       + gb[tid];
    p[tid + 256] = g0[tid + 256] * (v1 - mu) * r + b0[tid + 256] + gb[tid + 256];
    p[tid + 512] = g0[tid + 512] * (v2 - mu) * r + b0[tid + 512] + gb[tid + 512];
}

// ---------------------------------------------------------------------------
// Sequential GRU scan, 3 workgroups per chain (grid = 192, one wg per CU).
// wg (s = blockIdx.x>>6, b = blockIdx.x&63) owns U columns [s*256,(s+1)*256):
// thread (g=tid>>7, t=tid&127) holds 64 U values in TWO ext_vector_type(32)
// vectors (VGPR-resident by construction — no alloca, promote-alloca can't
// demote them; float[32] arrays were scratch-resident in rounds 2-3).
// Sync structure identical to round 2 (measured-faster than round 3's).
__global__ __launch_bounds__(1024, 4) void scan3_kernel(
    const float* __restrict__ XP,   // (L*B, 768), row=(l*64+b), bias+LN folded
    const float* __restrict__ U,    // (256, 768)
    const float* __restrict__ g1, const float* __restrict__ b1,
    const int* __restrict__ mask,   // [b*512+l]
    float* __restrict__ Y,          // (L*B, 256)
    float* __restrict__ exch,       // [64][2][3][256]
    int* __restrict__ flags)        // [64][FLAG_STRIDE], memset 0 pre-launch
{
    const int wg  = blockIdx.x;
    const int b   = wg & 63;
    const int s   = wg >> 6;               // slice 0..2
    const int tid = threadIdx.x;
    const int g   = tid >> 7;
    const int t   = tid & 127;
    const int kb  = g << 5;
    const int p1  = (s + 1 >= 3) ? s - 2 : s + 1;
    const int p2  = (s + 2 >= 3) ? s - 1 : s + 2;

    __shared__ float h_cur[256];
    __shared__ float part[8][256];
    __shared__ float xp_lds[768];
    __shared__ float g1s[768], b1s[768];
    __shared__ int   mk[512];
    __shared__ float reds[4], redq[4];

    // U slice -> registers (coalesced across t for each k)
    vf32x32 u0, u1;
    {
        const float* Ub = U + s * 256 + t;
#pragma unroll
        for (int k = 0; k < 32; ++k) {
            u0[k] = Ub[(kb + k) * H3];
            u1[k] = Ub[(kb + k) * H3 + 128];
        }
    }
    if (tid < 256) h_cur[tid] = 0.f;
    if (tid < 768) { g1s[tid] = g1[tid]; b1s[tid] = b1[tid]; }
    if (tid < 512) mk[tid] = mask[b * LL + tid];
    __syncthreads();

    float* exb = exch + b * (2 * 3 * 256);
    int*   flb = flags + b * FLAG_STRIDE;
    int seq = 0;

    for (int l = 0; l < LL; ++l) {
        if (!mk[l]) {
            // masked step: h unchanged, Y row = h (slice 0 writes)
            if (s == 0 && tid < 64) {
                float4 hv = *(const float4*)&h_cur[tid * 4];
                *(float4*)&Y[((long)l * BB + b) * HH + tid * 4] = hv;
            }
            continue;
        }
        seq++;
        const int par = seq & 1;

        // prefetch xp row (in flight during GEMV + exchange)
        float4 xr4;
        if (tid < 192) xr4 = *(const float4*)(XP + ((long)l * BB + b) * H3 + tid * 4);

        // slice GEMV: pre[c*128+t] = sum_k u[c][k] * h[kb+k], partial per g
        float a0 = 0.f, a1 = 0.f;
#pragma unroll
        for (int i = 0; i < 8; ++i) {
            float4 hv = *(const float4*)&h_cur[kb + i * 4];
            a0 += u0[i*4+0]*hv.x + u0[i*4+1]*hv.y + u0[i*4+2]*hv.z + u0[i*4+3]*hv.w;
            a1 += u1[i*4+0]*hv.x + u1[i*4+1]*hv.y + u1[i*4+2]*hv.z + u1[i*4+3]*hv.w;
        }
        part[g][t]       = a0;
        part[g][128 + t] = a1;
        __syncthreads();                               // B1: part complete

        // reduce over 8 k-groups; publish own slice (device-scope atomics)
        float pre = 0.f;
        if (tid < 256) {
            pre = part[0][tid];
#pragma unroll
            for (int gg = 1; gg < 8; ++gg) pre += part[gg][tid];
            __hip_atomic_store(&exb[(par * 3 + s) * 256 + tid], pre,
                               __ATOMIC_RELAXED, __HIP_MEMORY_SCOPE_AGENT);
        }
        if (tid < 192) *(float4*)&xp_lds[tid * 4] = xr4;
        __syncthreads();                               // B2: drains all vm stores
        if (tid == 0)
            __hip_atomic_store(&flb[s * 16], seq,
                               __ATOMIC_RELEASE, __HIP_MEMORY_SCOPE_AGENT);
        if (tid < 2) {
            int ps = tid ? p2 : p1;
            while (__hip_atomic_load(&flb[ps * 16],
                                     __ATOMIC_ACQUIRE, __HIP_MEMORY_SCOPE_AGENT) < seq) {}
        }
        __syncthreads();                               // B3: peers published

        // read peer slices + LN stats
        float v0 = 0.f, v1 = 0.f, v2 = 0.f;
        if (tid < 256) {
            float w1 = __hip_atomic_load(&exb[(par * 3 + p1) * 256 + tid],
                                         __ATOMIC_RELAXED, __HIP_MEMORY_SCOPE_AGENT);
            float w2 = __hip_atomic_load(&exb[(par * 3 + p2) * 256 + tid],
                                         __ATOMIC_RELAXED, __HIP_MEMORY_SCOPE_AGENT);
            v0 = (s == 0) ? pre : ((p1 == 0) ? w1 : w2);
            v1 = (s == 1) ? pre : ((p1 == 1) ? w1 : w2);
            v2 = (s == 2) ? pre : ((p1 == 2) ? w1 : w2);
            float st = v0 + v1 + v2;
            float qt = v0 * v0 + v1 * v1 + v2 * v2;
#pragma unroll
            for (int off = 32; off >= 1; off >>= 1) {
                st += __shfl_xor(st, off);
                qt += __shfl_xor(qt, off);
            }
            if ((tid & 63) == 0) { reds[tid >> 6] = st; redq[tid >> 6] = qt; }
        }
        __syncthreads();                               // B4: stats partials

        if (tid < 256) {
            float S = reds[0] + reds[1] + reds[2] + reds[3];
            float Q = redq[0] + redq[1] + redq[2] + redq[3];
            float mu = S * (1.f / 768.f);
            float rs = rsqrtf(Q * (1.f / 768.f) - mu * mu + 1e-5f);
            float hp_r = g1s[tid]       * (v0 - mu) * rs + b1s[tid];
            float hp_z = g1s[256 + tid] * (v1 - mu) * rs + b1s[256 + tid];
            float hp_h = g1s[512 + tid] * (v2 - mu) * rs + b1s[512 + tid];
            float xr = xp_lds[tid], xz = xp_lds[256 + tid], xh = xp_lds[512 + tid];
            float r  = 1.f / (1.f + expf(-(xr + hp_r)));
            float z  = 1.f / (1.f + expf(-(xz + hp_z)));
            float hh = tanhf(xh + r * hp_h);
            float o  = z * h_cur[tid] + (1.f - z) * hh;   // active step: mt=1
            h_cur[tid] = o;
            if (s == 0) Y[((long)l * BB + b) * HH + tid] = o;
        }
        __syncthreads();                               // B5: h_cur ready
    }
}

// ---------------------------------------------------------------------------
// Action head: per row (l,b): logits = T[row,:] @ Wa2 + ba2, softmax, decision.
__global__ __launch_bounds__(256) void act_kernel(
    const float* __restrict__ T, const float* __restrict__ Wa2,
    const float* __restrict__ ba2, const int* __restrict__ mask_in,
    int* __restrict__ mask_out, float* __restrict__ act_out,
    float* __restrict__ pol_out, int d)
{
    int row  = blockIdx.x * 4 + (threadIdx.x >> 6);
    int lane = threadIdx.x & 63;
    const float* Tr = T + (long)row * AA;
    float t0 = Tr[lane], t1 = Tr[lane + 64];
    float l0 = t0 * Wa2[lane * 2]       + t1 * Wa2[(lane + 64) * 2];
    float l1 = t0 * Wa2[lane * 2 + 1]   + t1 * Wa2[(lane + 64) * 2 + 1];
#pragma unroll
    for (int off = 32; off >= 1; off >>= 1) {
        l0 += __shfl_xor(l0, off);
        l1 += __shfl_xor(l1, off);
    }
    if (lane == 0) {
        int l = row >> 6, bb = row & 63;
        l0 += ba2[0]; l1 += ba2[1];
        float m  = fmaxf(l0, l1);
        float e0 = expf(l0 - m), e1 = expf(l1 - m);
        float inv = 1.f / (e0 + e1);
        float p0 = e0 * inv, p1 = e1 * inv;
        int mt = mask_in[bb * LL + l];
        int a  = (p1 > p0) && mt;
        act_out[bb * (NDEPTH * LL) + d * LL + l] = a ? 1.f : 0.f;
        pol_out[bb * (NDEPTH * LL * 2) + d * (LL * 2) + l * 2 + 0] = p0;
        pol_out[bb * (NDEPTH * LL * 2) + d * (LL * 2) + l * 2 + 1] = p1;
        mask_out[bb * LL + l] = a;
    }
}

// ---------------------------------------------------------------------------
__global__ void final_copy_kernel(const float* __restrict__ X, float* __restrict__ out)
{
    int i = blockIdx.x * blockDim.x + threadIdx.x;   // 16384
    int bb = i >> 8, j = i & 255;
    out[i] = X[((long)(LL - 1) * BB + bb) * HH + j];
}

// ---------------------------------------------------------------------------
extern "C" void kernel_launch(void* const* d_in, const int* in_sizes, int n_in,
                              void* d_out, int out_size, void* d_ws, size_t ws_size,
                              hipStream_t stream)
{
    const float* x      = (const float*)d_in[0];
    const void*  mraw   = d_in[1];
    const float* W_emb  = (const float*)d_in[2];
    const float* b_emb  = (const float*)d_in[3];
    const float* W      = (const float*)d_in[4];
    const float* U      = (const float*)d_in[5];
    const float* bias3  = (const float*)d_in[6];
    const float* Wa1    = (const float*)d_in[7];
    const float* Ua1    = (const float*)d_in[8];
    const float* ba1    = (const float*)d_in[9];
    const float* Wa2    = (const float*)d_in[10];
    const float* ba2    = (const float*)d_in[11];
    const float* gammas = (const float*)d_in[12];
    const float* betas  = (const float*)d_in[13];

    float* out = (float*)d_out;
    char*  ws  = (char*)d_ws;

    // workspace layout (bytes) — unchanged (<= 184.9 MB)
    float* XP = (float*)(ws);                                   // 100663296
    float* X  = (float*)(ws + 100663296UL);                     // 33554432
    float* Y  = (float*)(ws + 134217728UL);                     // 33554432
    float* XA = (float*)(ws + 167772160UL);                     // 16777216
    float* T  = XP;  // alias: XP dead between scan and next-depth GEMM
    int*   m0 = (int*)(ws + 184549376UL);                       // 131072
    int*   m1 = (int*)(ws + 184680448UL);                       // 131072

    float* act_out = out + BB * HH;                             // 16384
    float* pol_out = act_out + BB * NDEPTH * LL;                // +131072

    maskcvt_kernel<<<dim3(NROWS / 256), dim3(256), 0, stream>>>(
        (const unsigned char*)mraw, m0);

    // embedding: X = x @ W_emb + b_emb, time-major rows (l*64+b)
    gemm_kernel<1, 1><<<dim3(2, 256), dim3(256), 0, stream>>>(
        x, W_emb, b_emb, nullptr, X, NROWS, HH);

    float* Xc = X; float* Yc = Y;
    int* mc = m0; int* mn = m1;

    for (int d = 0; d < NDEPTH; ++d) {
        gemm_kernel<0, 0><<<dim3(6, 256), dim3(256), 0, stream>>>(
            Xc, W, nullptr, nullptr, XP, NROWS, H3);
        lnrows_kernel<<<dim3(NROWS), dim3(256), 0, stream>>>(
            XP, gammas, betas, bias3);
        gemm_kernel<0, 1><<<dim3(1, 256), dim3(256), 0, stream>>>(
            Xc, Wa1, ba1, nullptr, XA, NROWS, AA);

        // exchange + flags live in the now-dead Xc buffer (disjoint from Yc)
        float* exch_d  = Xc;
        int*   flags_d = (int*)(Xc + EXCH_FLOATS);
        hipMemsetAsync(flags_d, 0, FLAG_BYTES, stream);

        scan3_kernel<<<dim3(192), dim3(1024), 0, stream>>>(
            XP, U, gammas + H3, betas + H3, mc, Yc, exch_d, flags_d);

        gemm_kernel<2, 2><<<dim3(1, 256), dim3(256), 0, stream>>>(
            Yc, Ua1, nullptr, XA, T, NROWS, AA);
        act_kernel<<<dim3(NROWS / 4), dim3(256), 0, stream>>>(
            T, Wa2, ba2, mc, mn, act_out, pol_out, d);
        { float* tmp = Xc; Xc = Yc; Yc = tmp; }
        { int* tmp = mc; mc = mn; mn = tmp; }
    }

    final_copy_kernel<<<dim3(BB), dim3(256), 0, stream>>>(Xc, out);
}

// Round 5
// 3616.202 us; speedup vs baseline: 2.8899x; 1.5168x over previous
//
#include <hip/hip_runtime.h>
#include <hip/hip_bf16.h>
#include <math.h>

// Problem constants (fixed by setup_inputs): B=64, L=512, D_IN=256, H=256, A=128, DEPTH=4
#define BB 64
#define LL 512
#define HH 256
#define H3 768
#define AA 128
#define NDEPTH 4
#define NROWS (LL*BB)   // 32768

// exchange region (carved from the dead Xc buffer each depth):
//   u64 exch[64 chains][2 parity][3 slices][256]  = 786,432 B
#define EXCH_U64_PER_CHAIN (2 * 3 * 256)

typedef float vf32x32 __attribute__((ext_vector_type(32)));

// ---------------------------------------------------------------------------
// Mask conversion: detect byte-bool vs int32/float32 layout on device.
// mask[0][1] is always true (lengths >= 256 > 1): byte layout -> raw[1]==1.
__global__ void maskcvt_kernel(const unsigned char* __restrict__ raw,
                               int* __restrict__ m)
{
    int i = blockIdx.x * blockDim.x + threadIdx.x;   // 32768 threads
    bool bytemode = (raw[1] == 1);
    int v;
    if (bytemode) v = raw[i] ? 1 : 0;
    else          v = (((const int*)raw)[i] != 0) ? 1 : 0;
    m[i] = v;
}

// ---------------------------------------------------------------------------
// Tiled fp32 GEMM: C[M,N] = A[M,256] @ B[256,N]  (K fixed at 256)
// MODE 0: A[row,k] = A[row*256+k]
// MODE 1: A[row,k] = A[(row&63)*131072 + (row>>6)*256 + k]   (x gather)
// MODE 2: A[row,k] = row<64 ? 0 : A[(row-64)*256+k]          (Hprev shift)
// EPI 0: store acc; EPI 1: + bias[col]; EPI 2: tanh(acc + aux[row*N+col])
template<int MODE, int EPI>
__global__ __launch_bounds__(256) void gemm_kernel(
    const float* __restrict__ A, const float* __restrict__ Bm,
    const float* __restrict__ bias, const float* __restrict__ aux,
    float* __restrict__ C, int M, int N)
{
    __shared__ float As[16][136];
    __shared__ float Bs[16][136];
    const int tid = threadIdx.x;
    const int tx = tid & 15, ty = tid >> 4;
    const int row0 = blockIdx.y * 128, col0 = blockIdx.x * 128;

    float acc[8][8];
#pragma unroll
    for (int i = 0; i < 8; ++i)
#pragma unroll
        for (int j = 0; j < 8; ++j) acc[i][j] = 0.f;

    for (int kk = 0; kk < 256; kk += 16) {
#pragma unroll
        for (int i = 0; i < 2; ++i) {
            int aid = i * 256 + tid;
            int r   = aid >> 2;
            int k4  = (aid & 3) << 2;
            int rr  = row0 + r;
            float4 v;
            if (MODE == 0) {
                v = *(const float4*)(A + rr * 256 + kk + k4);
            } else if (MODE == 1) {
                v = *(const float4*)(A + (rr & 63) * 131072 + (rr >> 6) * 256 + kk + k4);
            } else {
                if (rr < 64) v = make_float4(0.f, 0.f, 0.f, 0.f);
                else         v = *(const float4*)(A + (rr - 64) * 256 + kk + k4);
            }
            As[k4 + 0][r] = v.x; As[k4 + 1][r] = v.y;
            As[k4 + 2][r] = v.z; As[k4 + 3][r] = v.w;

            int bid = i * 256 + tid;
            int bk  = bid >> 5;
            int c4  = (bid & 31) << 2;
            float4 w = *(const float4*)(Bm + (kk + bk) * N + col0 + c4);
            *(float4*)&Bs[bk][c4] = w;
        }
        __syncthreads();
#pragma unroll
        for (int k = 0; k < 16; ++k) {
            float a[8], bb2[8];
            *(float4*)&a[0]   = *(const float4*)&As[k][ty * 8];
            *(float4*)&a[4]   = *(const float4*)&As[k][ty * 8 + 4];
            *(float4*)&bb2[0] = *(const float4*)&Bs[k][tx * 8];
            *(float4*)&bb2[4] = *(const float4*)&Bs[k][tx * 8 + 4];
#pragma unroll
            for (int i = 0; i < 8; ++i)
#pragma unroll
                for (int j = 0; j < 8; ++j)
                    acc[i][j] += a[i] * bb2[j];
        }
        __syncthreads();
    }

#pragma unroll
    for (int i = 0; i < 8; ++i) {
        int row  = row0 + ty * 8 + i;
        int colb = col0 + tx * 8;
        float vout[8];
#pragma unroll
        for (int j = 0; j < 8; ++j) {
            float v = acc[i][j];
            if (EPI == 1) v += bias[colb + j];
            if (EPI == 2) v = tanhf(v + aux[row * N + colb + j]);
            vout[j] = v;
        }
        *(float4*)&C[row * N + colb]     = *(float4*)&vout[0];
        *(float4*)&C[row * N + colb + 4] = *(float4*)&vout[4];
    }
}

// ---------------------------------------------------------------------------
// Row LayerNorm over 768 cols, in place, fused with gamma/beta and gate bias.
__global__ __launch_bounds__(256) void lnrows_kernel(
    float* __restrict__ XP, const float* __restrict__ g0,
    const float* __restrict__ b0, const float* __restrict__ gb)
{
    const int row = blockIdx.x;
    const int tid = threadIdx.x;
    float* p = XP + (long)row * H3;
    float v0 = p[tid], v1 = p[tid + 256], v2 = p[tid + 512];
    float s = v0 + v1 + v2;
    float q = v0 * v0 + v1 * v1 + v2 * v2;
#pragma unroll
    for (int off = 32; off >= 1; off >>= 1) {
        s += __shfl_xor(s, off);
        q += __shfl_xor(q, off);
    }
    __shared__ float rs4[4], rq4[4];
    if ((tid & 63) == 0) { rs4[tid >> 6] = s; rq4[tid >> 6] = q; }
    __syncthreads();
    float S = rs4[0] + rs4[1] + rs4[2] + rs4[3];
    float Q = rq4[0] + rq4[1] + rq4[2] + rq4[3];
    float mu  = S * (1.f / 768.f);
    float var = Q * (1.f / 768.f) - mu * mu;
    float r   = rsqrtf(var + 1e-5f);
    p[tid]       = g0[tid]       * (v0 - mu) * r + b0[tid]       + gb[tid];
    p[tid + 256] = g0[tid + 256] * (v1 - mu) * r + b0[tid + 256] + gb[tid + 256];
    p[tid + 512] = g0[tid + 512] * (v2 - mu) * r + b0[tid + 512] + gb[tid + 512];
}

// ---------------------------------------------------------------------------
// Sequential GRU scan v3: 3 workgroups per chain (grid 192), 512 threads each.
// wg (s = blockIdx.x>>6, b = blockIdx.x&63) owns pre-LN columns
// [s*256,(s+1)*256) (s=0:r, s=1:z, s=2:hh). Thread (kg=tid>>5, cg=tid&31)
// holds U[kg*16 .. +16][colbase .. +8] = 128 floats in ext-vector registers
// loaded VOLATILE (rounds 2-4 post-mortem: plain invariant loads get
// rematerialized/sunk into the loop by the backend at its 64-VGPR occupancy
// target -> 256 KB/wg/step re-streamed from L2 ~ 4.2us/step; volatile loads
// are non-rematerializable). waves_per_eu(2,2) -> 256-VGPR budget, no spill.
// Exchange: packed (seq<<32 | float-bits) u64 relaxed AGENT atomics; peers
// poll the data itself (no flags, no acquire/release cache ops). Parity
// double-buffer; seq offset d<<10 avoids stale matches when a region is
// reused at depth d+2. 3 barriers per active step; masked steps copy only.
__global__ __attribute__((amdgpu_flat_work_group_size(512, 512)))
           __attribute__((amdgpu_waves_per_eu(2, 2)))
void scan3_kernel(
    const float* __restrict__ XP,   // (L*B, 768), row=(l*64+b), bias+LN folded
    const float* __restrict__ U,    // (256, 768)
    const float* __restrict__ g1, const float* __restrict__ b1,
    const int* __restrict__ mask,   // [b*512+l]
    float* __restrict__ Y,          // (L*B, 256)
    unsigned long long* __restrict__ exch,  // [64][2][3][256] u64
    int seq0)                       // d<<10
{
    const int wg  = blockIdx.x;
    const int b   = wg & 63;
    const int s   = wg >> 6;               // slice 0..2
    const int tid = threadIdx.x;
    const int kg  = tid >> 5;              // 16 k-groups (16 k each)
    const int cg  = tid & 31;              // 32 col-groups (8 cols each)
    const int q1  = (s + 1 >= 3) ? s - 2 : s + 1;
    const int q2  = (s + 2 >= 3) ? s - 1 : s + 2;

    __shared__ float h_cur[256];
    __shared__ float part[16][256];
    __shared__ float xp_lds[768];
    __shared__ float g1s[768], b1s[768];
    __shared__ int   mk[512];
    __shared__ float reds[4], redq[4];

    // U slice -> registers via volatile loads (pinned: no remat, no sinking)
    vf32x32 u0v, u1v, u2v, u3v;
    {
        const volatile float* Uv = U;
        const int colbase = s * 256 + cg * 8;
#pragma unroll
        for (int i = 0; i < 16; ++i) {
#pragma unroll
            for (int j = 0; j < 8; ++j) {
                const int f = i * 8 + j;
                float val = Uv[(kg * 16 + i) * H3 + colbase + j];
                if      (f < 32) u0v[f]      = val;
                else if (f < 64) u1v[f - 32] = val;
                else if (f < 96) u2v[f - 64] = val;
                else             u3v[f - 96] = val;
            }
        }
    }
    if (tid < 256) h_cur[tid] = 0.f;
    for (int i = tid; i < 768; i += 512) { g1s[i] = g1[i]; b1s[i] = b1[i]; }
    mk[tid] = mask[b * LL + tid];
    __syncthreads();

    unsigned long long* exb = exch + b * EXCH_U64_PER_CHAIN;
    int seq = seq0;

    for (int l = 0; l < LL; ++l) {
        if (!mk[l]) {
            // masked step: h unchanged, Y row = h (slice 0 writes)
            if (s == 0 && tid < 64) {
                float4 hv = *(const float4*)&h_cur[tid * 4];
                *(float4*)&Y[((long)l * BB + b) * HH + tid * 4] = hv;
            }
            continue;
        }
        seq++;
        const int par = seq & 1;

        // prefetch xp row (in flight during GEMV)
        float4 xr4;
        if (tid < 192) xr4 = *(const float4*)(XP + ((long)l * BB + b) * H3 + tid * 4);

        // slice GEMV: acc[j] = sum_{k in kg-chunk} U[k][colbase+j] * h[k]
        float acc[8] = {0.f, 0.f, 0.f, 0.f, 0.f, 0.f, 0.f, 0.f};
#pragma unroll
        for (int i = 0; i < 4; ++i) {
            float4 hv = *(const float4*)&h_cur[kg * 16 + i * 4];   // broadcast
#pragma unroll
            for (int e = 0; e < 4; ++e) {
                const float hh = (e == 0) ? hv.x : (e == 1) ? hv.y
                               : (e == 2) ? hv.z : hv.w;
                const int ik = i * 4 + e;
#pragma unroll
                for (int j = 0; j < 8; ++j) {
                    const int f = ik * 8 + j;
                    const float uu = (f < 32) ? u0v[f]
                                   : (f < 64) ? u1v[f - 32]
                                   : (f < 96) ? u2v[f - 64]
                                   :            u3v[f - 96];
                    acc[j] += uu * hh;
                }
            }
        }
        *(float4*)&part[kg][cg * 8]     = *(float4*)&acc[0];
        *(float4*)&part[kg][cg * 8 + 4] = *(float4*)&acc[4];
        __syncthreads();                               // B1: part complete

        if (tid < 192) *(float4*)&xp_lds[tid * 4] = xr4;

        float pre = 0.f, v0 = 0.f, v1 = 0.f, v2 = 0.f;
        if (tid < 256) {
            pre = part[0][tid];
#pragma unroll
            for (int gg = 1; gg < 16; ++gg) pre += part[gg][tid];

            // publish own slice value (data+seq packed, relaxed agent atomic)
            unsigned long long pk =
                ((unsigned long long)(unsigned)seq << 32) |
                (unsigned long long)__float_as_uint(pre);
            __hip_atomic_store(&exb[(par * 3 + s) * 256 + tid], pk,
                               __ATOMIC_RELAXED, __HIP_MEMORY_SCOPE_AGENT);

            // poll peers' packed values (self-validating: hi32 == seq)
            unsigned long long x1, x2;
            do {
                x1 = __hip_atomic_load(&exb[(par * 3 + q1) * 256 + tid],
                                       __ATOMIC_RELAXED, __HIP_MEMORY_SCOPE_AGENT);
            } while ((int)(x1 >> 32) != seq);
            do {
                x2 = __hip_atomic_load(&exb[(par * 3 + q2) * 256 + tid],
                                       __ATOMIC_RELAXED, __HIP_MEMORY_SCOPE_AGENT);
            } while ((int)(x2 >> 32) != seq);
            float w1 = __uint_as_float((unsigned)x1);
            float w2 = __uint_as_float((unsigned)x2);
            v0 = (s == 0) ? pre : ((q1 == 0) ? w1 : w2);
            v1 = (s == 1) ? pre : ((q1 == 1) ? w1 : w2);
            v2 = (s == 2) ? pre : ((q1 == 2) ? w1 : w2);

            float st = v0 + v1 + v2;
            float qt = v0 * v0 + v1 * v1 + v2 * v2;
#pragma unroll
            for (int off = 32; off >= 1; off >>= 1) {
                st += __shfl_xor(st, off);
                qt += __shfl_xor(qt, off);
            }
            if ((tid & 63) == 0) { reds[tid >> 6] = st; redq[tid >> 6] = qt; }
        }
        __syncthreads();                               // B2: stats partials

        if (tid < 256) {
            float S = reds[0] + reds[1] + reds[2] + reds[3];
            float Q = redq[0] + redq[1] + redq[2] + redq[3];
            float mu = S * (1.f / 768.f);
            float rs = rsqrtf(Q * (1.f / 768.f) - mu * mu + 1e-5f);
            float hp_r = g1s[tid]       * (v0 - mu) * rs + b1s[tid];
            float hp_z = g1s[256 + tid] * (v1 - mu) * rs + b1s[256 + tid];
            float hp_h = g1s[512 + tid] * (v2 - mu) * rs + b1s[512 + tid];
            float xr = xp_lds[tid], xz = xp_lds[256 + tid], xh = xp_lds[512 + tid];
            float r  = 1.f / (1.f + expf(-(xr + hp_r)));
            float z  = 1.f / (1.f + expf(-(xz + hp_z)));
            float hh = tanhf(xh + r * hp_h);
            float o  = z * h_cur[tid] + (1.f - z) * hh;   // active step: mt=1
            h_cur[tid] = o;
            if (s == 0) Y[((long)l * BB + b) * HH + tid] = o;
        }
        __syncthreads();                               // B3: h_cur ready
    }
}

// ---------------------------------------------------------------------------
// Action head: per row (l,b): logits = T[row,:] @ Wa2 + ba2, softmax, decision.
__global__ __launch_bounds__(256) void act_kernel(
    const float* __restrict__ T, const float* __restrict__ Wa2,
    const float* __restrict__ ba2, const int* __restrict__ mask_in,
    int* __restrict__ mask_out, float* __restrict__ act_out,
    float* __restrict__ pol_out, int d)
{
    int row  = blockIdx.x * 4 + (threadIdx.x >> 6);
    int lane = threadIdx.x & 63;
    const float* Tr = T + (long)row * AA;
    float t0 = Tr[lane], t1 = Tr[lane + 64];
    float l0 = t0 * Wa2[lane * 2]       + t1 * Wa2[(lane + 64) * 2];
    float l1 = t0 * Wa2[lane * 2 + 1]   + t1 * Wa2[(lane + 64) * 2 + 1];
#pragma unroll
    for (int off = 32; off >= 1; off >>= 1) {
        l0 += __shfl_xor(l0, off);
        l1 += __shfl_xor(l1, off);
    }
    if (lane == 0) {
        int l = row >> 6, bb = row & 63;
        l0 += ba2[0]; l1 += ba2[1];
        float m  = fmaxf(l0, l1);
        float e0 = expf(l0 - m), e1 = expf(l1 - m);
        float inv = 1.f / (e0 + e1);
        float p0 = e0 * inv, p1 = e1 * inv;
        int mt = mask_in[bb * LL + l];
        int a  = (p1 > p0) && mt;
        act_out[bb * (NDEPTH * LL) + d * LL + l] = a ? 1.f : 0.f;
        pol_out[bb * (NDEPTH * LL * 2) + d * (LL * 2) + l * 2 + 0] = p0;
        pol_out[bb * (NDEPTH * LL * 2) + d * (LL * 2) + l * 2 + 1] = p1;
        mask_out[bb * LL + l] = a;
    }
}

// ---------------------------------------------------------------------------
__global__ void final_copy_kernel(const float* __restrict__ X, float* __restrict__ out)
{
    int i = blockIdx.x * blockDim.x + threadIdx.x;   // 16384
    int bb = i >> 8, j = i & 255;
    out[i] = X[((long)(LL - 1) * BB + bb) * HH + j];
}

// ---------------------------------------------------------------------------
extern "C" void kernel_launch(void* const* d_in, const int* in_sizes, int n_in,
                              void* d_out, int out_size, void* d_ws, size_t ws_size,
                              hipStream_t stream)
{
    const float* x      = (const float*)d_in[0];
    const void*  mraw   = d_in[1];
    const float* W_emb  = (const float*)d_in[2];
    const float* b_emb  = (const float*)d_in[3];
    const float* W      = (const float*)d_in[4];
    const float* U      = (const float*)d_in[5];
    const float* bias3  = (const float*)d_in[6];
    const float* Wa1    = (const float*)d_in[7];
    const float* Ua1    = (const float*)d_in[8];
    const float* ba1    = (const float*)d_in[9];
    const float* Wa2    = (const float*)d_in[10];
    const float* ba2    = (const float*)d_in[11];
    const float* gammas = (const float*)d_in[12];
    const float* betas  = (const float*)d_in[13];

    float* out = (float*)d_out;
    char*  ws  = (char*)d_ws;

    // workspace layout (bytes) — unchanged (<= 184.9 MB)
    float* XP = (float*)(ws);                                   // 100663296
    float* X  = (float*)(ws + 100663296UL);                     // 33554432
    float* Y  = (float*)(ws + 134217728UL);                     // 33554432
    float* XA = (float*)(ws + 167772160UL);                     // 16777216
    float* T  = XP;  // alias: XP dead between scan and next-depth GEMM
    int*   m0 = (int*)(ws + 184549376UL);                       // 131072
    int*   m1 = (int*)(ws + 184680448UL);                       // 131072

    float* act_out = out + BB * HH;                             // 16384
    float* pol_out = act_out + BB * NDEPTH * LL;                // +131072

    maskcvt_kernel<<<dim3(NROWS / 256), dim3(256), 0, stream>>>(
        (const unsigned char*)mraw, m0);

    // embedding: X = x @ W_emb + b_emb, time-major rows (l*64+b)
    gemm_kernel<1, 1><<<dim3(2, 256), dim3(256), 0, stream>>>(
        x, W_emb, b_emb, nullptr, X, NROWS, HH);

    float* Xc = X; float* Yc = Y;
    int* mc = m0; int* mn = m1;

    for (int d = 0; d < NDEPTH; ++d) {
        gemm_kernel<0, 0><<<dim3(6, 256), dim3(256), 0, stream>>>(
            Xc, W, nullptr, nullptr, XP, NROWS, H3);
        lnrows_kernel<<<dim3(NROWS), dim3(256), 0, stream>>>(
            XP, gammas, betas, bias3);
        gemm_kernel<0, 1><<<dim3(1, 256), dim3(256), 0, stream>>>(
            Xc, Wa1, ba1, nullptr, XA, NROWS, AA);

        // exchange lives in the now-dead Xc buffer (disjoint from Yc).
        // No memset needed: entries are self-validating (seq-tagged) and
        // seq ranges are disjoint per depth (seq0 = d<<10).
        unsigned long long* exch_d = (unsigned long long*)Xc;

        scan3_kernel<<<dim3(192), dim3(512), 0, stream>>>(
            XP, U, gammas + H3, betas + H3, mc, Yc, exch_d, d << 10);

        gemm_kernel<2, 2><<<dim3(1, 256), dim3(256), 0, stream>>>(
            Yc, Ua1, nullptr, XA, T, NROWS, AA);
        act_kernel<<<dim3(NROWS / 4), dim3(256), 0, stream>>>(
            T, Wa2, ba2, mc, mn, act_out, pol_out, d);
        { float* tmp = Xc; Xc = Yc; Yc = tmp; }
        { int* tmp = mc; mc = mn; mn = tmp; }
    }

    final_copy_kernel<<<dim3(BB), dim3(256), 0, stream>>>(Xc, out);
}